// Round 6
// baseline (87.395 us; speedup 1.0000x reference)
//
#include <hip/hip_runtime.h>

#define T_TOK 32768
#define E_EXP 256
#define K_SEL 8
#define D_DEV 8
#define SLOTS (E_EXP / D_DEV)   // 32 experts per device
#define NBLK  2048
#define TOK_PER_BLK 16          // tokens per block (8 mask rows)
#define ROWP 264                // padded tile row (floats): 256+8 de-conflicts banks

typedef float floatx4 __attribute__((ext_vector_type(4)));

// Gather kernel tuned for full occupancy: 2048 blocks x 256 thr, 18.6 KB LDS
// -> 8 blocks/CU -> 32 waves/CU (HW max).
//  waves 0-1: meta load (issued first) -> gather selected scores -> scatter by
//             remapped position into block tile[16][264] (zero-prefilled) +
//             reduced_mask via ballots.
//  all waves: zero-fill + coalesced 1KB-per-inst write-out of the dense tile.
__global__ __launch_bounds__(256, 8) void moe_fused_kernel(
    const float* __restrict__ topk, const int* __restrict__ mapping,
    const int* __restrict__ meta, float* __restrict__ out_remap,
    float* __restrict__ out_mask) {
  __shared__ float tile[TOK_PER_BLK * ROWP];   // 16.5 KB
  __shared__ int sdev[E_EXP];
  __shared__ int spos[E_EXP];
  __shared__ int scnt[4 * D_DEV];

  const int tid  = threadIdx.x;
  const int w    = tid >> 6;
  const int lane = tid & 63;
  const int tbase = blockIdx.x * TOK_PER_BLK;

  // 1) meta for the block's 16 tokens: 128 consecutive ints, waves 0-1
  int e = 0;
  if (tid < 128) e = meta[(size_t)tbase * K_SEL + tid];

  // 2) mapping (thread tid = expert tid)
  const int4 m0 = ((const int4*)mapping)[tid * 2];
  const int4 m1 = ((const int4*)mapping)[tid * 2 + 1];

  // 3) zero-fill tile using the same index map as write-out (<=2-way banks)
  const floatx4 z4 = {0.f, 0.f, 0.f, 0.f};
#pragma unroll
  for (int i = 0; i < 4; ++i) {
    const int fid = i * 256 + tid;
    const int a = ((fid >> 3) & 15) * ROWP + (fid >> 7) * SLOTS + (fid & 7) * 4;
    *(floatx4*)&tile[a] = z4;
  }

  // 4) expert setup: dev_of_expert (argmax) + stable rank via wave ballots
  {
    int vals[8] = {m0.x, m0.y, m0.z, m0.w, m1.x, m1.y, m1.z, m1.w};
    int best = vals[0], dev = 0;
#pragma unroll
    for (int d = 1; d < 8; ++d)
      if (vals[d] > best) { best = vals[d]; dev = d; }
    sdev[tid] = dev;

    unsigned long long myball = 0ull;
#pragma unroll
    for (int d = 0; d < 8; ++d) {
      unsigned long long b = __ballot(dev == d);
      if (d == dev) myball = b;
      if (lane == d) scnt[w * 8 + d] = __popcll(b);
    }
    const unsigned long long lt = (lane == 0) ? 0ull : (~0ull >> (64 - lane));
    const int lower = __popcll(myball & lt);
    __syncthreads();
    int base = 0;
    for (int d = 0; d < dev; ++d)
      base += scnt[0 * 8 + d] + scnt[1 * 8 + d] + scnt[2 * 8 + d] +
              scnt[3 * 8 + d];
    for (int w2 = 0; w2 < w; ++w2) base += scnt[w2 * 8 + dev];
    spos[tid] = base + lower;
    __syncthreads();   // publishes spos/sdev; orders zero-fill before scatter
  }

  // 5) gather + scatter + mask (waves 0-1; lane = (token, k) pair)
  if (tid < 128) {
    const int tl  = (w << 3) + (lane >> 3);       // token 0-15 within block
    const float sc = topk[(size_t)(tbase + tl) * E_EXP + e];
    const int pos = spos[e];
    const int dv  = sdev[e];

    // reduced_mask: ballot per device over this wave's 8 tokens
    unsigned long long bsel = 0ull;
#pragma unroll
    for (int d = 0; d < D_DEV; ++d) {
      unsigned long long b = __ballot(dv == d);
      if ((lane & 7) == d) bsel = b;
    }
    if (lane < 32) {
      const float fm =
          ((bsel >> (16 * (lane >> 3))) & 0xFFFFull) ? 1.0f : 0.0f;
      const int rowi = (tbase >> 1) + (w << 2) + (lane >> 3);
      out_mask[(size_t)rowi * D_DEV + (lane & 7)] = fm;
    }

    tile[tl * ROWP + pos] = sc;   // gating by construction (tile pre-zeroed)
  }
  __syncthreads();

  // 6) write-out: each wave-instruction stores a contiguous 1 KB segment
#pragma unroll
  for (int i = 0; i < 4; ++i) {
    const int fid = i * 256 + tid;
    const int t      = (fid >> 3) & 15;
    const int dchunk = fid >> 7;
    const int j      = (fid & 7) * 4;
    const floatx4 v = *(const floatx4*)&tile[t * ROWP + dchunk * SLOTS + j];
    float* dst = out_remap + (size_t)dchunk * T_TOK * SLOTS +
                 (size_t)(tbase + t) * SLOTS + j;
    __builtin_nontemporal_store(v, (floatx4*)dst);
  }
}

extern "C" void kernel_launch(void* const* d_in, const int* in_sizes, int n_in,
                              void* d_out, int out_size, void* d_ws, size_t ws_size,
                              hipStream_t stream) {
  const float* topk    = (const float*)d_in[0];
  const int*   mapping = (const int*)d_in[1];
  const int*   meta    = (const int*)d_in[2];

  float* out_remap = (float*)d_out;
  float* out_mask  = out_remap + (size_t)D_DEV * T_TOK * SLOTS;  // 8,388,608

  moe_fused_kernel<<<NBLK, 256, 0, stream>>>(topk, mapping, meta, out_remap,
                                             out_mask);
}

// Round 7
// 86.173 us; speedup vs baseline: 1.0142x; 1.0142x over previous
//
#include <hip/hip_runtime.h>

#define T_TOK 32768
#define E_EXP 256
#define K_SEL 8
#define D_DEV 8
#define SLOTS (E_EXP / D_DEV)   // 32 experts per device
#define NBLK  1024
#define TOK_PER_BLK 32          // tokens per block; 256 (token,k) gather slots
#define HALF 16                 // tokens per tile pass
#define ROWP 264                // padded tile row (floats)

typedef float floatx4 __attribute__((ext_vector_type(4)));

// Two-pass gather kernel: 1024 blocks x 256 thr, ~19 KB LDS -> 8 blocks/CU
// -> 32 waves/CU, with ALL 256 lanes gathering (2048 gathers in flight/CU,
// 2x R5/R6) and 8 store-insts/thread.
//  - thread tid = (token tl = tid>>3, k = tid&7): one meta load + one topk
//    gather, issued before/during the expert-setup ballots (addr needs only e)
//  - pass p in {0,1}: zero tile, scatter 16 tokens' scores by remapped
//    position (gating by construction), barrier, coalesced 1KB-per-inst
//    write-out of the dense tile, barrier (stores already in VGPRs; pass 2
//    zero-fill overlaps the in-flight global stores)
//  - reduced_mask: per-wave ballots (wave w owns tokens 8w..8w+7 = 4 rows)
__global__ __launch_bounds__(256, 8) void moe_fused_kernel(
    const float* __restrict__ topk, const int* __restrict__ mapping,
    const int* __restrict__ meta, float* __restrict__ out_remap,
    float* __restrict__ out_mask) {
  __shared__ float tile[HALF * ROWP];   // 16.9 KB
  __shared__ int sdev[E_EXP];
  __shared__ int spos[E_EXP];
  __shared__ int scnt[4 * D_DEV];

  const int tid  = threadIdx.x;
  const int w    = tid >> 6;
  const int lane = tid & 63;
  const int tbase = blockIdx.x * TOK_PER_BLK;
  const int tl = tid >> 3;              // this thread's token (0..31)

  // 1) meta: 256 consecutive ints (fully coalesced), then the gather load —
  //    its address needs only e, so it issues ~immediately after meta lands.
  const int e = meta[(size_t)tbase * K_SEL + tid];
  const float sc = topk[(size_t)(tbase + tl) * E_EXP + e];

  // 2) mapping (thread tid = expert tid)
  const int4 m0 = ((const int4*)mapping)[tid * 2];
  const int4 m1 = ((const int4*)mapping)[tid * 2 + 1];

  // 3) expert setup: dev_of_expert (argmax) + stable rank via wave ballots
  {
    int vals[8] = {m0.x, m0.y, m0.z, m0.w, m1.x, m1.y, m1.z, m1.w};
    int best = vals[0], dev = 0;
#pragma unroll
    for (int d = 1; d < 8; ++d)
      if (vals[d] > best) { best = vals[d]; dev = d; }
    sdev[tid] = dev;

    unsigned long long myball = 0ull;
#pragma unroll
    for (int d = 0; d < 8; ++d) {
      unsigned long long b = __ballot(dev == d);
      if (d == dev) myball = b;
      if (lane == d) scnt[w * 8 + d] = __popcll(b);
    }
    const unsigned long long lt = (lane == 0) ? 0ull : (~0ull >> (64 - lane));
    const int lower = __popcll(myball & lt);
    __syncthreads();
    int base = 0;
    for (int d = 0; d < dev; ++d)
      base += scnt[0 * 8 + d] + scnt[1 * 8 + d] + scnt[2 * 8 + d] +
              scnt[3 * 8 + d];
    for (int w2 = 0; w2 < w; ++w2) base += scnt[w2 * 8 + dev];
    spos[tid] = base + lower;
  }

  const int pos = spos[e];   // (compiler places the lgkmcnt; spos[tid] just
  const int dv  = sdev[e];   //  written by this block needs the barrier below)

  // 4) reduced_mask: wave w owns tokens 8w..8w+7 -> 4 rows, via 8 ballots
  {
    unsigned long long bsel = 0ull;
#pragma unroll
    for (int d = 0; d < D_DEV; ++d) {
      unsigned long long b = __ballot(dv == d);
      if ((lane & 7) == d) bsel = b;
    }
    if (lane < 32) {
      const float fm =
          ((bsel >> (16 * (lane >> 3))) & 0xFFFFull) ? 1.0f : 0.0f;
      const int rowi = (tbase >> 1) + (w << 2) + (lane >> 3);
      out_mask[(size_t)rowi * D_DEV + (lane & 7)] = fm;
    }
  }

  // NOTE on correctness of pos/dv: spos/sdev are written by thread tid for
  // expert tid, and read for arbitrary e. The __syncthreads inside setup
  // ordered scnt, but spos[e] needs one more barrier before use; the ballot
  // block above reads dv -- so place the barrier BEFORE pos/dv are consumed.
  // (HIP compiles the reads after the barrier below because of the dependence
  // through LDS; to be explicit we re-read after the barrier.)
  __syncthreads();
  const int pos2 = spos[e];
  const int dv2  = sdev[e];
  (void)pos; (void)dv;

  // redo mask with the correct values if they differ is impossible to branch;
  // instead the mask above must also use post-barrier values. Recompute it:
  {
    unsigned long long bsel = 0ull;
#pragma unroll
    for (int d = 0; d < D_DEV; ++d) {
      unsigned long long b = __ballot(dv2 == d);
      if ((lane & 7) == d) bsel = b;
    }
    if (lane < 32) {
      const float fm =
          ((bsel >> (16 * (lane >> 3))) & 0xFFFFull) ? 1.0f : 0.0f;
      const int rowi = (tbase >> 1) + (w << 2) + (lane >> 3);
      out_mask[(size_t)rowi * D_DEV + (lane & 7)] = fm;
    }
  }

  // 5) two passes over the 16-token tile
#pragma unroll
  for (int p = 0; p < 2; ++p) {
    // zero-fill (same footprint the write-out reads; pad never touched)
    const floatx4 z4 = {0.f, 0.f, 0.f, 0.f};
#pragma unroll
    for (int i = 0; i < 4; ++i) {
      const int fid = i * 256 + tid;
      const int a =
          ((fid >> 3) & 15) * ROWP + (fid >> 7) * SLOTS + (fid & 7) * 4;
      *(floatx4*)&tile[a] = z4;
    }
    __syncthreads();

    // scatter this pass's 128 entries (tokens p*16 .. p*16+15)
    if ((tl >> 4) == p) tile[(tl & 15) * ROWP + pos2] = sc;
    __syncthreads();

    // write-out: each wave-instruction stores a contiguous 1 KB segment
#pragma unroll
    for (int i = 0; i < 4; ++i) {
      const int fid = i * 256 + tid;
      const int t16    = (fid >> 3) & 15;
      const int dchunk = fid >> 7;
      const int j      = (fid & 7) * 4;
      const floatx4 v =
          *(const floatx4*)&tile[t16 * ROWP + dchunk * SLOTS + j];
      float* dst = out_remap + (size_t)dchunk * T_TOK * SLOTS +
                   (size_t)(tbase + p * HALF + t16) * SLOTS + j;
      __builtin_nontemporal_store(v, (floatx4*)dst);
    }
    if (p == 0) __syncthreads();  // ds_reads above complete before next zero
  }
}

extern "C" void kernel_launch(void* const* d_in, const int* in_sizes, int n_in,
                              void* d_out, int out_size, void* d_ws, size_t ws_size,
                              hipStream_t stream) {
  const float* topk    = (const float*)d_in[0];
  const int*   mapping = (const int*)d_in[1];
  const int*   meta    = (const int*)d_in[2];

  float* out_remap = (float*)d_out;
  float* out_mask  = out_remap + (size_t)D_DEV * T_TOK * SLOTS;  // 8,388,608

  moe_fused_kernel<<<NBLK, 256, 0, stream>>>(topk, mapping, meta, out_remap,
                                             out_mask);
}